// Round 2
// baseline (229.045 us; speedup 1.0000x reference)
//
#include <hip/hip_runtime.h>

// De-emphasis IIR: y[0]=x[0], y[n]=0.95*y[n-1]+x[n], rows of length 524288.
// Halo-truncated blocked scan: 0.95^1024 ~ 1.5e-23, so each block computes
// its chunk exactly (to f32 precision) from a 1024-sample halo with zero
// initial condition. No cross-block communication needed.

#define T_LEN   524288
#define CHUNK   8192        // floats written per block
#define HALO    1024        // floats of look-back
#define W_FL    (CHUNK + HALO)   // 9216 floats read per block
#define NF4     (W_FL / 4)       // 2304 float4 staged in LDS
#define NF4_CH  (CHUNK / 4)      // 2048
#define NF4_HA  (HALO / 4)       // 256
#define THREADS 256
#define CPT     9           // float4 per thread (36 floats serial run)
#define DCOEFF  0.95f

__global__ __launch_bounds__(THREADS, 4)
void deemph_kernel(const float4* __restrict__ xin, float4* __restrict__ yout) {
    __shared__ float4 lds[NF4];          // 36 KB
    __shared__ float  ws[THREADS / 64];

    const int tid   = threadIdx.x;
    const int bid   = blockIdx.x;
    const int row   = bid >> 6;          // 64 chunks per row
    const int chunk = bid & 63;

    const int row4  = row * (T_LEN / 4);
    const int base4 = row4 + chunk * NF4_CH - NF4_HA;   // may dip 256 f4 "before" chunk

    // 1. global -> LDS, coalesced float4. Left edge of row: zero-fill halo.
    #pragma unroll
    for (int k = 0; k < CPT; ++k) {
        const int q = k * THREADS + tid;
        float4 val;
        if (chunk == 0 && q < NF4_HA) {
            val = make_float4(0.f, 0.f, 0.f, 0.f);
        } else {
            val = xin[base4 + q];
        }
        lds[q] = val;
    }
    __syncthreads();

    // 2. LDS -> regs: thread t owns floats [36t, 36t+36) of the block region.
    //    Slot stride 9 (odd) => lanes spread evenly across LDS bank quads.
    float4 q4[CPT];
    #pragma unroll
    for (int k = 0; k < CPT; ++k) q4[k] = lds[tid * CPT + k];

    // 3. pass A: local scan final value (zero initial condition)
    float f = 0.f;
    #pragma unroll
    for (int k = 0; k < CPT; ++k) {
        f = fmaf(DCOEFF, f, q4[k].x);
        f = fmaf(DCOEFF, f, q4[k].y);
        f = fmaf(DCOEFF, f, q4[k].z);
        f = fmaf(DCOEFF, f, q4[k].w);
    }

    // 4. carry scan across threads. Ratio between consecutive threads:
    //    c36 = 0.95^36.  Wave-level Hillis-Steele with geometric weights.
    const float c36 = 0.15777914f;       // 0.95^36
    const float l36 = -2.6640215f;       // 36*log2(0.95)
    const int lane = tid & 63;
    const int wave = tid >> 6;
    float y = f;
    float m = c36;                        // c36^d at each step
    #pragma unroll
    for (int d = 1; d < 64; d <<= 1) {
        float up = __shfl_up(y, d, 64);
        if (lane >= d) y = fmaf(m, up, y);
        m = m * m;                        // after loop: m = c36^64 (≈0)
    }
    if (lane == 63) ws[wave] = y;         // wave-inclusive final
    __syncthreads();                      // also fences step-2 reads vs step-6 writes
    float C = 0.f;                        // block-inclusive carry into this wave
    for (int u = 0; u < wave; ++u) C = fmaf(m, C, ws[u]);
    const float yup = __shfl_up(y, 1, 64);
    // exclusive carry into thread t: E = y_{lane-1} + c36^lane * C
    const float E = ((lane > 0) ? yup : 0.f) + exp2f((float)lane * l36) * C;

    // 5. pass B: true outputs = scan with initial condition E
    float yy = E;
    #pragma unroll
    for (int k = 0; k < CPT; ++k) {
        yy = fmaf(DCOEFF, yy, q4[k].x); q4[k].x = yy;
        yy = fmaf(DCOEFF, yy, q4[k].y); q4[k].y = yy;
        yy = fmaf(DCOEFF, yy, q4[k].z); q4[k].z = yy;
        yy = fmaf(DCOEFF, yy, q4[k].w); q4[k].w = yy;
    }

    // 6. regs -> LDS (step-4 barrier already ordered all step-2 reads before this)
    #pragma unroll
    for (int k = 0; k < CPT; ++k) lds[tid * CPT + k] = q4[k];
    __syncthreads();

    // 7. LDS -> global, coalesced float4, skipping the halo
    const int out4 = row4 + chunk * NF4_CH;
    #pragma unroll
    for (int k = 0; k < 8; ++k) {
        const int q = k * THREADS + tid;
        yout[out4 + q] = lds[q + NF4_HA];
    }
}

extern "C" void kernel_launch(void* const* d_in, const int* in_sizes, int n_in,
                              void* d_out, int out_size, void* d_ws, size_t ws_size,
                              hipStream_t stream) {
    const float4* xin  = (const float4*)d_in[0];
    float4*       yout = (float4*)d_out;
    const int rows = in_sizes[0] / T_LEN;            // 64
    const int blocks = rows * (T_LEN / CHUNK);       // 64 * 64 = 4096
    deemph_kernel<<<dim3(blocks), dim3(THREADS), 0, stream>>>(xin, yout);
}